// Round 22
// baseline (160.050 us; speedup 1.0000x reference)
//
#include <hip/hip_runtime.h>
#include <math.h>

#define NB 2
#define NN 2048
#define DD 512
#define L2E 1.44269504088896340736f

typedef __attribute__((ext_vector_type(8))) short short8;
typedef __attribute__((ext_vector_type(4))) float f32x4;

__device__ __forceinline__ unsigned short f2bf(float x) {
  union { float f; unsigned u; } a;
  a.f = x;
  unsigned r = a.u + 0x7FFF + ((a.u >> 16) & 1);  // RNE
  return (unsigned short)(r >> 16);
}
__device__ __forceinline__ float bf2f(unsigned short u) {
  union { unsigned u; float f; } a;
  a.u = ((unsigned)u) << 16;
  return a.f;
}
__device__ __forceinline__ unsigned cvtpk(float lo, float hi) {
  unsigned r;
  asm("v_cvt_pk_bf16_f32 %0, %1, %2" : "=v"(r) : "v"(lo), "v"(hi));
  return r;
}
// 4x v_exp_f32 (2^x) + 2x cvt_pk with hazard-safe spacing
__device__ __forceinline__ uint2 exp4pk(float e0, float e1, float e2, float e3) {
  float p0, p1, p2, p3;
  uint2 d;
  asm("v_exp_f32 %2, %6\n\t"
      "v_exp_f32 %3, %7\n\t"
      "v_exp_f32 %4, %8\n\t"
      "v_exp_f32 %5, %9\n\t"
      "v_cvt_pk_bf16_f32 %0, %2, %3\n\t"
      "v_cvt_pk_bf16_f32 %1, %4, %5"
      : "=&v"(d.x), "=&v"(d.y), "=&v"(p0), "=&v"(p1), "=&v"(p2), "=&v"(p3)
      : "v"(e0), "v"(e1), "v"(e2), "v"(e3));
  return d;
}

__device__ __forceinline__ float waveReduceSum(float v) {
#pragma unroll
  for (int o = 32; o; o >>= 1) v += __shfl_down(v, o, 64);
  return v;
}
__device__ __forceinline__ float blockReduceSum(float v, float* red4) {
  int tid = threadIdx.x;
  __syncthreads();
  v = waveReduceSum(v);
  if ((tid & 63) == 0) red4[tid >> 6] = v;
  __syncthreads();
  return red4[0] + red4[1] + red4[2] + red4[3];
}

// ---- prep: W transpose->bf16 (128 blocks) | v = W @ a (72 blocks) -------------
__global__ __launch_bounds__(256) void prep_kernel(
    const float* __restrict__ W1, const float* __restrict__ W2,
    unsigned short* __restrict__ WT1, unsigned short* __restrict__ WT2,
    const float* __restrict__ as1, const float* __restrict__ ad1,
    float* __restrict__ vs1, float* __restrict__ vd1,
    const float* __restrict__ as2, const float* __restrict__ ad2,
    float* __restrict__ vs2, float* __restrict__ vd2) {
  __shared__ float tile[64][65];
  int bid = blockIdx.x;
  int t = threadIdx.x;
  if (bid < 128) {
    const float* W = (bid & 64) ? W2 : W1;
    unsigned short* WT = (bid & 64) ? WT2 : WT1;
    int r = bid & 63;
    int kt = (r >> 3) * 64, ct = (r & 7) * 64;
#pragma unroll
    for (int u = 0; u < 16; u++) {
      int lin = t + u * 256;
      int kl = lin >> 6, cl = lin & 63;
      tile[kl][cl] = W[(size_t)(kt + kl) * DD + ct + cl];
    }
    __syncthreads();
#pragma unroll
    for (int u = 0; u < 16; u++) {
      int lin = t + u * 256;
      int cl = lin >> 6, kl = lin & 63;
      WT[(size_t)(ct + cl) * DD + kt + kl] = f2bf(tile[kl][cl]);
    }
  } else {
    int idx = bid - 128;  // 0..71
    int slot = idx >> 3, dch = idx & 7;
    const float *W, *as, *ad;
    float *vs, *vd;
    int Dh, hoff;
    if (slot < 8) {
      W = W1; as = as1 + slot * 64; ad = ad1 + slot * 64;
      vs = vs1 + (size_t)slot * DD; vd = vd1 + (size_t)slot * DD;
      Dh = 64; hoff = slot * 64;
    } else {
      W = W2; as = as2; ad = ad2; vs = vs2; vd = vd2;
      Dh = 512; hoff = 0;
    }
    int dl = t >> 2, kq = t & 3;
    int d = dch * 64 + dl;
    int kn = Dh >> 2;
    const float* wr = W + (size_t)d * DD + hoff + kq * kn;
    const float* asp = as + kq * kn;
    const float* adp = ad + kq * kn;
    float s = 0.f, dd2 = 0.f;
    for (int k = 0; k < kn; k++) {
      float wv = wr[k];
      s += wv * asp[k];
      dd2 += wv * adp[k];
    }
    s += __shfl_xor(s, 1);
    s += __shfl_xor(s, 2);
    dd2 += __shfl_xor(dd2, 1);
    dd2 += __shfl_xor(dd2, 2);
    if (kq == 0) {
      vs[d] = s;
      vd[d] = dd2;
    }
  }
}

// ---- fused LayerNorm + s,t: one block per row ----------------------------------
__global__ __launch_bounds__(256) void lnst_kernel(
    const float* __restrict__ x, const float* __restrict__ g,
    const float* __restrict__ bb, unsigned short* __restrict__ y,
    const float* __restrict__ vs, const float* __restrict__ vd,
    float* __restrict__ sOut, float* __restrict__ tOut, int HN) {
  __shared__ float red4[4];
  __shared__ float lnS[512];
  int row = blockIdx.x;
  int t = threadIdx.x;
  const float* xr = x + (size_t)row * DD;
  float2 v = *(const float2*)&xr[2 * t];
  float s = blockReduceSum(v.x + v.y, red4);
  float mu = s * (1.0f / 512.0f);
  float d0 = v.x - mu, d1 = v.y - mu;
  float ss = blockReduceSum(d0 * d0 + d1 * d1, red4);
  float rstd = rsqrtf(ss * (1.0f / 512.0f) + 1e-6f);
  float2 gg = *(const float2*)&g[2 * t];
  float2 bv = *(const float2*)&bb[2 * t];
  float n0 = d0 * rstd * gg.x + bv.x;
  float n1 = d1 * rstd * gg.y + bv.y;
  ushort2 o;
  o.x = f2bf(n0);
  o.y = f2bf(n1);
  *(ushort2*)&y[(size_t)row * DD + 2 * t] = o;
  lnS[2 * t] = n0;
  lnS[2 * t + 1] = n1;
  __syncthreads();
  int wv = t >> 6, l = t & 63;
  int b = row >> 11, n = row & (NN - 1);
  float4 x0 = *(const float4*)&lnS[l * 8];
  float4 x1 = *(const float4*)&lnS[l * 8 + 4];
  for (int h = wv; h < HN; h += 4) {
    const float* vsr = vs + (size_t)h * DD + l * 8;
    const float* vdr = vd + (size_t)h * DD + l * 8;
    float4 a0 = *(const float4*)vsr, a1 = *(const float4*)(vsr + 4);
    float4 c0 = *(const float4*)vdr, c1 = *(const float4*)(vdr + 4);
    float ps = x0.x * a0.x + x0.y * a0.y + x0.z * a0.z + x0.w * a0.w +
               x1.x * a1.x + x1.y * a1.y + x1.z * a1.z + x1.w * a1.w;
    float pd = x0.x * c0.x + x0.y * c0.y + x0.z * c0.z + x0.w * c0.w +
               x1.x * c1.x + x1.y * c1.y + x1.z * c1.z + x1.w * c1.w;
#pragma unroll
    for (int o2 = 32; o2; o2 >>= 1) {
      ps += __shfl_xor(ps, o2);
      pd += __shfl_xor(pd, o2);
    }
    if (l == 0) {
      sOut[((size_t)b * HN + h) * NN + n] = ps * L2E;
      tOut[((size_t)b * HN + h) * NN + n] = pd * L2E;
    }
  }
}

// ------- bf16 MFMA GEMM, K-split; epilogue writes V frag-contiguous ------------
// hbT layout: [b][cG=c/64][jT=j/16][f=(c%64)/16][cl=16][jl=16] bf16.
__global__ __launch_bounds__(256) void gemm_kernel(const unsigned short* __restrict__ A,
                                                   const unsigned short* __restrict__ BT,
                                                   unsigned short* __restrict__ hbT) {
  __shared__ float accL[4][16][65];
  int t = threadIdx.x, w = t >> 6, l = t & 63;
  int li = l & 15, lg = l >> 4;
  int R0 = blockIdx.x * 16;  // global row (b*NN + j)
  int c0 = blockIdx.y * 64;
  const unsigned short* ar = A + (size_t)(R0 + li) * DD + w * 128 + lg * 8;
  const unsigned short* br = BT + (size_t)(c0 + li) * DD + w * 128 + lg * 8;
  f32x4 acc[4] = {};
#pragma unroll
  for (int k0 = 0; k0 < 128; k0 += 32) {
    short8 af = *(const short8*)(ar + k0);
#pragma unroll
    for (int f = 0; f < 4; f++) {
      short8 bf = *(const short8*)(br + (size_t)f * 16 * DD + k0);
      acc[f] = __builtin_amdgcn_mfma_f32_16x16x32_bf16(af, bf, acc[f], 0, 0, 0);
    }
  }
#pragma unroll
  for (int f = 0; f < 4; f++)
#pragma unroll
    for (int r = 0; r < 4; r++) accL[w][lg * 4 + r][f * 16 + li] = acc[f][r];
  __syncthreads();
  int b = R0 >> 11, jT = (R0 & (NN - 1)) >> 4;
#pragma unroll
  for (int u = 0; u < 2; u++) {
    int idx = t + u * 256;  // 512 dwords = 16j x 64c
    int f = idx >> 7;
    int rem = idx & 127;
    int cl = rem >> 3, jlp = rem & 7;
    int cc = f * 16 + cl;
    float v0 = accL[0][2 * jlp][cc] + accL[1][2 * jlp][cc] + accL[2][2 * jlp][cc] +
               accL[3][2 * jlp][cc];
    float v1 = accL[0][2 * jlp + 1][cc] + accL[1][2 * jlp + 1][cc] +
               accL[2][2 * jlp + 1][cc] + accL[3][2 * jlp + 1][cc];
    size_t off = (((size_t)(b * (DD / 64) + blockIdx.y) * (NN / 16)) + jT) * 1024 +
                 f * 256 + cl * 16 + jlp * 2;
    *(unsigned*)(hbT + off) = cvtpk(v0, v1);
  }
}

// ------ unified PV: block = 16 rows x 2 groups; wave = (j-half, group) ---------
// group = head (HN=8) or 64-col chunk (HN=1). hbT group index b*8+grp and out
// column base grp*64 are identical in both cases; only s/t row differs.
// V is DOUBLE-BUFFERED across iterations (2-body unrolled ping-pong): each
// MFMA consumes V issued one full iteration earlier -> ~2x bytes in flight
// (Little's law; r20 showed V loaded+consumed same-iter capped BW at 1.7TB/s).
// Merge: per group, 2-way j-merge through LDS overlaid on dead Pl.
template <int HN>
__global__ __launch_bounds__(256) void pvg_kernel(
    const unsigned short* __restrict__ hbT, const float* __restrict__ bias,
    const float* __restrict__ sArr, const float* __restrict__ tArr,
    const float* __restrict__ res, float* __restrict__ out) {
  __shared__ __align__(16) unsigned char smem[16896];
  unsigned short (*Pl)[2][1024] = (unsigned short (*)[2][1024])smem;  // [4][2][1024]
  float (*accL2)[16][65] = (float (*)[16][65])smem;                   // [2][16][65]
  float (*sLa)[16] = (float (*)[16])(smem + 8320);                    // [4][16]
  int t = threadIdx.x, w = t >> 6, l = t & 63;
  int jh = w & 1, hp = w >> 1;
  int li = l & 15, lg = l >> 4;
  int i0 = blockIdx.x * 16;
  int g0 = blockIdx.y * 2, b = blockIdx.z;
  int grp = g0 + hp;
  size_t bhN = ((size_t)b * HN + (HN == 8 ? grp : 0)) * NN;
  const float* trow = tArr + bhN;

  int rs = l >> 3, js = (l & 7) * 8, jc = l & 7;
  int wchunk = ((jc & 4) | ((jc & 3) ^ (rs & 3))) * 8;  // swizzled chunk (shorts)
  float sv[2];
  sv[0] = sArr[bhN + i0 + rs];
  sv[1] = sArr[bhN + i0 + 8 + rs];
  const float* bb0 = bias + ((size_t)b * NN + i0 + rs) * NN;
  const float* bb1 = bb0 + (size_t)8 * NN;

  const unsigned short* vbase =
      hbT + ((size_t)(b * 8 + grp) * (NN / 16)) * 1024 + (lg >> 1) * 1024 + li * 16 +
      (lg & 1) * 8;
  int ra0 = li * 64 + (lg ^ (li & 3)) * 8;
  int ra1 = ra0 + 32;

  union { short8 v; unsigned short q[8]; } ones;
#pragma unroll
  for (int k = 0; k < 8; k++) ones.q[k] = 0x3F80;

  const int jbeg = jh * (NN / 2), jend = jbeg + NN / 2;
  f32x4 acc[4] = {};
  f32x4 accS = {0.f, 0.f, 0.f, 0.f};

  auto loadTB = [&](int j, float4& t0, float4& t1, float4& b0a, float4& b0b,
                    float4& b1a, float4& b1b) {
    t0 = *(const float4*)&trow[j + js];
    t1 = *(const float4*)&trow[j + js + 4];
    b0a = *(const float4*)&bb0[j + js];
    b0b = *(const float4*)&bb0[j + js + 4];
    b1a = *(const float4*)&bb1[j + js];
    b1b = *(const float4*)&bb1[j + js + 4];
  };
  auto computeP = [&](const float4& t0, const float4& t1, const float4& b0a,
                      const float4& b0b, const float4& b1a, const float4& b1b, int pb) {
#pragma unroll
    for (int u = 0; u < 2; u++) {
      const float4& ba = u ? b1a : b0a;
      const float4& bc = u ? b1b : b0b;
      int row = u * 8 + rs;
      float e0 = sv[u] + t0.x, e1 = sv[u] + t0.y;
      float e2 = sv[u] + t0.z, e3 = sv[u] + t0.w;
      float e4 = sv[u] + t1.x, e5 = sv[u] + t1.y;
      float e6 = sv[u] + t1.z, e7 = sv[u] + t1.w;
      e0 = fmaf(ba.x, L2E, fmaxf(e0, 0.2f * e0));
      e1 = fmaf(ba.y, L2E, fmaxf(e1, 0.2f * e1));
      e2 = fmaf(ba.z, L2E, fmaxf(e2, 0.2f * e2));
      e3 = fmaf(ba.w, L2E, fmaxf(e3, 0.2f * e3));
      e4 = fmaf(bc.x, L2E, fmaxf(e4, 0.2f * e4));
      e5 = fmaf(bc.y, L2E, fmaxf(e5, 0.2f * e5));
      e6 = fmaf(bc.z, L2E, fmaxf(e6, 0.2f * e6));
      e7 = fmaf(bc.w, L2E, fmaxf(e7, 0.2f * e7));
      uint2 d0 = exp4pk(e0, e1, e2, e3);
      uint2 d1 = exp4pk(e4, e5, e6, e7);
      uint4 dd;
      dd.x = d0.x; dd.y = d0.y; dd.z = d1.x; dd.w = d1.y;
      *(uint4*)&Pl[w][pb][row * 64 + wchunk] = dd;
    }
  };
  auto loadV = [&](int jt, short8 (&vv)[8]) {
    const unsigned short* vp = vbase + (size_t)jt * 64;
#pragma unroll
    for (int f = 0; f < 4; f++) {
      vv[f] = *(const short8*)(vp + f * 256);
      vv[4 + f] = *(const short8*)(vp + 2048 + f * 256);
    }
  };
  auto domfma = [&](short8 a0, short8 a1, const short8 (&vv)[8]) {
    __builtin_amdgcn_s_setprio(1);
    accS = __builtin_amdgcn_mfma_f32_16x16x32_bf16(a0, ones.v, accS, 0, 0, 0);
    acc[0] = __builtin_amdgcn_mfma_f32_16x16x32_bf16(a0, vv[0], acc[0], 0, 0, 0);
    acc[1] = __builtin_amdgcn_mfma_f32_16x16x32_bf16(a0, vv[1], acc[1], 0, 0, 0);
    acc[2] = __builtin_amdgcn_mfma_f32_16x16x32_bf16(a0, vv[2], acc[2], 0, 0, 0);
    acc[3] = __builtin_amdgcn_mfma_f32_16x16x32_bf16(a0, vv[3], acc[3], 0, 0, 0);
    accS = __builtin_amdgcn_mfma_f32_16x16x32_bf16(a1, ones.v, accS, 0, 0, 0);
    acc[0] = __builtin_amdgcn_mfma_f32_16x16x32_bf16(a1, vv[4], acc[0], 0, 0, 0);
    acc[1] = __builtin_amdgcn_mfma_f32_16x16x32_bf16(a1, vv[5], acc[1], 0, 0, 0);
    acc[2] = __builtin_amdgcn_mfma_f32_16x16x32_bf16(a1, vv[6], acc[2], 0, 0, 0);
    acc[3] = __builtin_amdgcn_mfma_f32_16x16x32_bf16(a1, vv[7], acc[3], 0, 0, 0);
    __builtin_amdgcn_s_setprio(0);
  };

  float4 tA0, tA1, bA0, bA1, bA2, bA3;
  short8 vvA[8], vvB[8];

  // prologue: P(jbeg) -> Pl[0]; tb(jbeg+64) staged; V(jbeg) -> vvA
  loadTB(jbeg, tA0, tA1, bA0, bA1, bA2, bA3);
  computeP(tA0, tA1, bA0, bA1, bA2, bA3, 0);
  loadTB(jbeg + 64, tA0, tA1, bA0, bA1, bA2, bA3);
  loadV(jbeg, vvA);

  for (int jt = jbeg; jt < jend; jt += 128) {
    // ---- body 0: consume Pl[0]=P(jt), vvA=V(jt); produce Pl[1], vvB ----
    loadV(jt + 64, vvB);
    short8 a0 = *(const short8*)&Pl[w][0][ra0];
    short8 a1 = *(const short8*)&Pl[w][0][ra1];
    {
      float4 n0 = tA0, n1 = tA1, m0 = bA0, m1 = bA1, m2 = bA2, m3 = bA3;
      // dead-prefetch clamp inside bias allocation (r15 OOB lesson)
      int jn = (jt + 128 < jend) ? (jt + 128) : jbeg;
      loadTB(jn, tA0, tA1, bA0, bA1, bA2, bA3);
      computeP(n0, n1, m0, m1, m2, m3, 1);
    }
    domfma(a0, a1, vvA);
    // ---- body 1: consume Pl[1]=P(jt+64), vvB; produce Pl[0], vvA ----
    bool more = (jt + 128 < jend);
    if (more) loadV(jt + 128, vvA);
    short8 c0 = *(const short8*)&Pl[w][1][ra0];
    short8 c1 = *(const short8*)&Pl[w][1][ra1];
    if (more) {
      float4 n0 = tA0, n1 = tA1, m0 = bA0, m1 = bA1, m2 = bA2, m3 = bA3;
      int jn = (jt + 192 < jend) ? (jt + 192) : jbeg;
      loadTB(jn, tA0, tA1, bA0, bA1, bA2, bA3);
      computeP(n0, n1, m0, m1, m2, m3, 0);
    }
    domfma(c0, c1, vvB);
  }

  // ---- merge: Pl dead; overlay. Per group, 2-way j-merge. ----
  __syncthreads();
  if (li == 0) {
#pragma unroll
    for (int r = 0; r < 4; r++) sLa[w][lg * 4 + r] = accS[r];
  }
#pragma unroll
  for (int hp2 = 0; hp2 < 2; hp2++) {
    if (hp == hp2) {
#pragma unroll
      for (int f = 0; f < 4; f++)
#pragma unroll
        for (int r = 0; r < 4; r++) accL2[jh][lg * 4 + r][f * 16 + li] = acc[f][r];
    }
    __syncthreads();
    {
      int rr = t >> 4, cq = t & 15;
      float S = sLa[2 * hp2][rr] + sLa[2 * hp2 + 1][rr];
      float inv = 1.0f / S;
      size_t ixb = ((size_t)b * NN + i0 + rr) * DD + (g0 + hp2) * 64 + cq;
#pragma unroll
      for (int f = 0; f < 4; f++) {
        int col = f * 16 + cq;
        float O = accL2[0][rr][col] + accL2[1][rr][col];
        out[ixb + f * 16] = O * inv + res[ixb + f * 16];
      }
    }
    __syncthreads();
  }
}

extern "C" void kernel_launch(void* const* d_in, const int* in_sizes, int n_in,
                              void* d_out, int out_size, void* d_ws, size_t ws_size,
                              hipStream_t stream) {
  const float* x = (const float*)d_in[0];
  const float* bias = (const float*)d_in[1];
  const float* W1 = (const float*)d_in[2];
  const float* asrc1 = (const float*)d_in[3];
  const float* adst1 = (const float*)d_in[4];
  const float* g1 = (const float*)d_in[5];
  const float* b1 = (const float*)d_in[6];
  const float* W2 = (const float*)d_in[7];
  const float* asrc2 = (const float*)d_in[8];
  const float* adst2 = (const float*)d_in[9];
  const float* g2 = (const float*)d_in[10];
  const float* b2 = (const float*)d_in[11];
  float* out = (float*)d_out;
  float* ws = (float*)d_ws;

  const size_t RC = (size_t)NB * NN * DD;  // 2097152 floats
  float* attnBuf = ws;                                        // 8 MB fp32
  unsigned short* lnB = (unsigned short*)(ws + RC);           // 4 MB bf16
  unsigned short* hbT = (unsigned short*)(ws + RC + RC / 2);  // 4 MB bf16 tiled V
  unsigned short* WT1 = (unsigned short*)(ws + 2 * RC);       // 0.5 MB
  unsigned short* WT2 = WT1 + (size_t)DD * DD;                // 0.5 MB
  float* vs1 = (float*)(WT2 + (size_t)DD * DD);               // [8][512]
  float* vd1 = vs1 + 8 * DD;
  float* vs2 = vd1 + 8 * DD;  // [1][512]
  float* vd2 = vs2 + DD;
  float* sBuf = vd2 + DD;  // [16][2048]
  float* tBuf = sBuf + 16 * NN;

  const int rows = NB * NN;  // 4096

  hipLaunchKernelGGL(prep_kernel, dim3(128 + 72), dim3(256), 0, stream, W1, W2, WT1, WT2,
                     asrc1, adst1, vs1, vd1, asrc2, adst2, vs2, vd2);

  // ---- layer 1 (H=8, Dh=64) ----
  hipLaunchKernelGGL(lnst_kernel, dim3(rows), dim3(256), 0, stream, x, g1, b1, lnB, vs1, vd1,
                     sBuf, tBuf, 8);
  hipLaunchKernelGGL(gemm_kernel, dim3(256, 8), dim3(256), 0, stream, lnB, WT1, hbT);
  hipLaunchKernelGGL(pvg_kernel<8>, dim3(128, 4, 2), dim3(256), 0, stream, hbT, bias, sBuf,
                     tBuf, x, attnBuf);

  // ---- layer 2 (H=1, Dh=512) ----
  hipLaunchKernelGGL(lnst_kernel, dim3(rows), dim3(256), 0, stream, attnBuf, g2, b2, lnB, vs2,
                     vd2, sBuf, tBuf, 1);
  hipLaunchKernelGGL(gemm_kernel, dim3(256, 8), dim3(256), 0, stream, lnB, WT2, hbT);
  hipLaunchKernelGGL(pvg_kernel<1>, dim3(128, 4, 2), dim3(256), 0, stream, hbT, bias, sBuf,
                     tBuf, attnBuf, out);
}

// Round 23
// 151.746 us; speedup vs baseline: 1.0547x; 1.0547x over previous
//
#include <hip/hip_runtime.h>
#include <math.h>

#define NB 2
#define NN 2048
#define DD 512
#define L2E 1.44269504088896340736f

typedef __attribute__((ext_vector_type(8))) short short8;
typedef __attribute__((ext_vector_type(4))) float f32x4;

__device__ __forceinline__ unsigned short f2bf(float x) {
  union { float f; unsigned u; } a;
  a.f = x;
  unsigned r = a.u + 0x7FFF + ((a.u >> 16) & 1);  // RNE
  return (unsigned short)(r >> 16);
}
__device__ __forceinline__ float bf2f(unsigned short u) {
  union { unsigned u; float f; } a;
  a.u = ((unsigned)u) << 16;
  return a.f;
}
__device__ __forceinline__ unsigned cvtpk(float lo, float hi) {
  unsigned r;
  asm("v_cvt_pk_bf16_f32 %0, %1, %2" : "=v"(r) : "v"(lo), "v"(hi));
  return r;
}
// 4x v_exp_f32 (2^x) + 2x cvt_pk with hazard-safe spacing
__device__ __forceinline__ uint2 exp4pk(float e0, float e1, float e2, float e3) {
  float p0, p1, p2, p3;
  uint2 d;
  asm("v_exp_f32 %2, %6\n\t"
      "v_exp_f32 %3, %7\n\t"
      "v_exp_f32 %4, %8\n\t"
      "v_exp_f32 %5, %9\n\t"
      "v_cvt_pk_bf16_f32 %0, %2, %3\n\t"
      "v_cvt_pk_bf16_f32 %1, %4, %5"
      : "=&v"(d.x), "=&v"(d.y), "=&v"(p0), "=&v"(p1), "=&v"(p2), "=&v"(p3)
      : "v"(e0), "v"(e1), "v"(e2), "v"(e3));
  return d;
}

__device__ __forceinline__ float waveReduceSum(float v) {
#pragma unroll
  for (int o = 32; o; o >>= 1) v += __shfl_down(v, o, 64);
  return v;
}
__device__ __forceinline__ float blockReduceSum(float v, float* red4) {
  int tid = threadIdx.x;
  __syncthreads();
  v = waveReduceSum(v);
  if ((tid & 63) == 0) red4[tid >> 6] = v;
  __syncthreads();
  return red4[0] + red4[1] + red4[2] + red4[3];
}

// ---- prep: W transpose->bf16 (128 blocks) | v = W @ a (72 blocks) -------------
__global__ __launch_bounds__(256) void prep_kernel(
    const float* __restrict__ W1, const float* __restrict__ W2,
    unsigned short* __restrict__ WT1, unsigned short* __restrict__ WT2,
    const float* __restrict__ as1, const float* __restrict__ ad1,
    float* __restrict__ vs1, float* __restrict__ vd1,
    const float* __restrict__ as2, const float* __restrict__ ad2,
    float* __restrict__ vs2, float* __restrict__ vd2) {
  __shared__ float tile[64][65];
  int bid = blockIdx.x;
  int t = threadIdx.x;
  if (bid < 128) {
    const float* W = (bid & 64) ? W2 : W1;
    unsigned short* WT = (bid & 64) ? WT2 : WT1;
    int r = bid & 63;
    int kt = (r >> 3) * 64, ct = (r & 7) * 64;
#pragma unroll
    for (int u = 0; u < 16; u++) {
      int lin = t + u * 256;
      int kl = lin >> 6, cl = lin & 63;
      tile[kl][cl] = W[(size_t)(kt + kl) * DD + ct + cl];
    }
    __syncthreads();
#pragma unroll
    for (int u = 0; u < 16; u++) {
      int lin = t + u * 256;
      int cl = lin >> 6, kl = lin & 63;
      WT[(size_t)(ct + cl) * DD + kt + kl] = f2bf(tile[kl][cl]);
    }
  } else {
    int idx = bid - 128;  // 0..71
    int slot = idx >> 3, dch = idx & 7;
    const float *W, *as, *ad;
    float *vs, *vd;
    int Dh, hoff;
    if (slot < 8) {
      W = W1; as = as1 + slot * 64; ad = ad1 + slot * 64;
      vs = vs1 + (size_t)slot * DD; vd = vd1 + (size_t)slot * DD;
      Dh = 64; hoff = slot * 64;
    } else {
      W = W2; as = as2; ad = ad2; vs = vs2; vd = vd2;
      Dh = 512; hoff = 0;
    }
    int dl = t >> 2, kq = t & 3;
    int d = dch * 64 + dl;
    int kn = Dh >> 2;
    const float* wr = W + (size_t)d * DD + hoff + kq * kn;
    const float* asp = as + kq * kn;
    const float* adp = ad + kq * kn;
    float s = 0.f, dd2 = 0.f;
    for (int k = 0; k < kn; k++) {
      float wv = wr[k];
      s += wv * asp[k];
      dd2 += wv * adp[k];
    }
    s += __shfl_xor(s, 1);
    s += __shfl_xor(s, 2);
    dd2 += __shfl_xor(dd2, 1);
    dd2 += __shfl_xor(dd2, 2);
    if (kq == 0) {
      vs[d] = s;
      vd[d] = dd2;
    }
  }
}

// ---- fused LayerNorm + s,t: one block per row ----------------------------------
__global__ __launch_bounds__(256) void lnst_kernel(
    const float* __restrict__ x, const float* __restrict__ g,
    const float* __restrict__ bb, unsigned short* __restrict__ y,
    const float* __restrict__ vs, const float* __restrict__ vd,
    float* __restrict__ sOut, float* __restrict__ tOut, int HN) {
  __shared__ float red4[4];
  __shared__ float lnS[512];
  int row = blockIdx.x;
  int t = threadIdx.x;
  const float* xr = x + (size_t)row * DD;
  float2 v = *(const float2*)&xr[2 * t];
  float s = blockReduceSum(v.x + v.y, red4);
  float mu = s * (1.0f / 512.0f);
  float d0 = v.x - mu, d1 = v.y - mu;
  float ss = blockReduceSum(d0 * d0 + d1 * d1, red4);
  float rstd = rsqrtf(ss * (1.0f / 512.0f) + 1e-6f);
  float2 gg = *(const float2*)&g[2 * t];
  float2 bv = *(const float2*)&bb[2 * t];
  float n0 = d0 * rstd * gg.x + bv.x;
  float n1 = d1 * rstd * gg.y + bv.y;
  ushort2 o;
  o.x = f2bf(n0);
  o.y = f2bf(n1);
  *(ushort2*)&y[(size_t)row * DD + 2 * t] = o;
  lnS[2 * t] = n0;
  lnS[2 * t + 1] = n1;
  __syncthreads();
  int wv = t >> 6, l = t & 63;
  int b = row >> 11, n = row & (NN - 1);
  float4 x0 = *(const float4*)&lnS[l * 8];
  float4 x1 = *(const float4*)&lnS[l * 8 + 4];
  for (int h = wv; h < HN; h += 4) {
    const float* vsr = vs + (size_t)h * DD + l * 8;
    const float* vdr = vd + (size_t)h * DD + l * 8;
    float4 a0 = *(const float4*)vsr, a1 = *(const float4*)(vsr + 4);
    float4 c0 = *(const float4*)vdr, c1 = *(const float4*)(vdr + 4);
    float ps = x0.x * a0.x + x0.y * a0.y + x0.z * a0.z + x0.w * a0.w +
               x1.x * a1.x + x1.y * a1.y + x1.z * a1.z + x1.w * a1.w;
    float pd = x0.x * c0.x + x0.y * c0.y + x0.z * c0.z + x0.w * c0.w +
               x1.x * c1.x + x1.y * c1.y + x1.z * c1.z + x1.w * c1.w;
#pragma unroll
    for (int o2 = 32; o2; o2 >>= 1) {
      ps += __shfl_xor(ps, o2);
      pd += __shfl_xor(pd, o2);
    }
    if (l == 0) {
      sOut[((size_t)b * HN + h) * NN + n] = ps * L2E;
      tOut[((size_t)b * HN + h) * NN + n] = pd * L2E;
    }
  }
}

// ------- bf16 MFMA GEMM, K-split; epilogue writes V frag-contiguous ------------
// hbT layout: [b][cG=c/64][jT=j/16][f=(c%64)/16][cl=16][jl=16] bf16.
__global__ __launch_bounds__(256) void gemm_kernel(const unsigned short* __restrict__ A,
                                                   const unsigned short* __restrict__ BT,
                                                   unsigned short* __restrict__ hbT) {
  __shared__ float accL[4][16][65];
  int t = threadIdx.x, w = t >> 6, l = t & 63;
  int li = l & 15, lg = l >> 4;
  int R0 = blockIdx.x * 16;  // global row (b*NN + j)
  int c0 = blockIdx.y * 64;
  const unsigned short* ar = A + (size_t)(R0 + li) * DD + w * 128 + lg * 8;
  const unsigned short* br = BT + (size_t)(c0 + li) * DD + w * 128 + lg * 8;
  f32x4 acc[4] = {};
#pragma unroll
  for (int k0 = 0; k0 < 128; k0 += 32) {
    short8 af = *(const short8*)(ar + k0);
#pragma unroll
    for (int f = 0; f < 4; f++) {
      short8 bf = *(const short8*)(br + (size_t)f * 16 * DD + k0);
      acc[f] = __builtin_amdgcn_mfma_f32_16x16x32_bf16(af, bf, acc[f], 0, 0, 0);
    }
  }
#pragma unroll
  for (int f = 0; f < 4; f++)
#pragma unroll
    for (int r = 0; r < 4; r++) accL[w][lg * 4 + r][f * 16 + li] = acc[f][r];
  __syncthreads();
  int b = R0 >> 11, jT = (R0 & (NN - 1)) >> 4;
#pragma unroll
  for (int u = 0; u < 2; u++) {
    int idx = t + u * 256;  // 512 dwords = 16j x 64c
    int f = idx >> 7;
    int rem = idx & 127;
    int cl = rem >> 3, jlp = rem & 7;
    int cc = f * 16 + cl;
    float v0 = accL[0][2 * jlp][cc] + accL[1][2 * jlp][cc] + accL[2][2 * jlp][cc] +
               accL[3][2 * jlp][cc];
    float v1 = accL[0][2 * jlp + 1][cc] + accL[1][2 * jlp + 1][cc] +
               accL[2][2 * jlp + 1][cc] + accL[3][2 * jlp + 1][cc];
    size_t off = (((size_t)(b * (DD / 64) + blockIdx.y) * (NN / 16)) + jT) * 1024 +
                 f * 256 + cl * 16 + jlp * 2;
    *(unsigned*)(hbT + off) = cvtpk(v0, v1);
  }
}

// ------ layer-1 PV "pvg": block = 16 rows x 2 heads; wave = (j-half, head) -----
// Wave w: head h0+(w>>1), j in [(w&1)*1024, +1024), 16 iters of 64 j.
// Both heads' waves read the SAME bias addresses -> bias logical reads halve.
// Merge: per head, 2-way j-merge through LDS overlaid on dead Pl.
__global__ __launch_bounds__(256) void pvg_kernel(
    const unsigned short* __restrict__ hbT, const float* __restrict__ bias,
    const float* __restrict__ sArr, const float* __restrict__ tArr,
    const float* __restrict__ res, float* __restrict__ out) {
  __shared__ __align__(16) unsigned char smem[16896];
  unsigned short (*Pl)[2][1024] = (unsigned short (*)[2][1024])smem;  // [4][2][1024]
  float (*accL2)[16][65] = (float (*)[16][65])smem;                   // [2][16][65]
  float (*sLa)[16] = (float (*)[16])(smem + 8320);                    // [4][16]
  int t = threadIdx.x, w = t >> 6, l = t & 63;
  int jh = w & 1, hp = w >> 1;
  int li = l & 15, lg = l >> 4;
  int i0 = blockIdx.x * 16;
  int h0 = blockIdx.y * 2, b = blockIdx.z;
  int head = h0 + hp;
  size_t bhN = (size_t)(b * 8 + head) * NN;
  const float* trow = tArr + bhN;

  int rs = l >> 3, js = (l & 7) * 8, jc = l & 7;
  int wchunk = ((jc & 4) | ((jc & 3) ^ (rs & 3))) * 8;  // swizzled chunk (shorts)
  float sv[2];
  sv[0] = sArr[bhN + i0 + rs];
  sv[1] = sArr[bhN + i0 + 8 + rs];
  const float* bb0 = bias + ((size_t)b * NN + i0 + rs) * NN;
  const float* bb1 = bb0 + (size_t)8 * NN;

  const unsigned short* vbase =
      hbT + ((size_t)(b * 8 + head) * (NN / 16)) * 1024 + (lg >> 1) * 1024 + li * 16 +
      (lg & 1) * 8;
  int ra0 = li * 64 + (lg ^ (li & 3)) * 8;
  int ra1 = ra0 + 32;

  union { short8 v; unsigned short q[8]; } ones;
#pragma unroll
  for (int k = 0; k < 8; k++) ones.q[k] = 0x3F80;

  const int jbeg = jh * (NN / 2), jend = jbeg + NN / 2;
  f32x4 acc[4] = {};
  f32x4 accS = {0.f, 0.f, 0.f, 0.f};

  auto loadTB = [&](int j, float4& t0, float4& t1, float4& b0a, float4& b0b,
                    float4& b1a, float4& b1b) {
    t0 = *(const float4*)&trow[j + js];
    t1 = *(const float4*)&trow[j + js + 4];
    b0a = *(const float4*)&bb0[j + js];
    b0b = *(const float4*)&bb0[j + js + 4];
    b1a = *(const float4*)&bb1[j + js];
    b1b = *(const float4*)&bb1[j + js + 4];
  };
  auto computeP = [&](const float4& t0, const float4& t1, const float4& b0a,
                      const float4& b0b, const float4& b1a, const float4& b1b, int pb) {
#pragma unroll
    for (int u = 0; u < 2; u++) {
      const float4& ba = u ? b1a : b0a;
      const float4& bc = u ? b1b : b0b;
      int row = u * 8 + rs;
      float e0 = sv[u] + t0.x, e1 = sv[u] + t0.y;
      float e2 = sv[u] + t0.z, e3 = sv[u] + t0.w;
      float e4 = sv[u] + t1.x, e5 = sv[u] + t1.y;
      float e6 = sv[u] + t1.z, e7 = sv[u] + t1.w;
      e0 = fmaf(ba.x, L2E, fmaxf(e0, 0.2f * e0));
      e1 = fmaf(ba.y, L2E, fmaxf(e1, 0.2f * e1));
      e2 = fmaf(ba.z, L2E, fmaxf(e2, 0.2f * e2));
      e3 = fmaf(ba.w, L2E, fmaxf(e3, 0.2f * e3));
      e4 = fmaf(bc.x, L2E, fmaxf(e4, 0.2f * e4));
      e5 = fmaf(bc.y, L2E, fmaxf(e5, 0.2f * e5));
      e6 = fmaf(bc.z, L2E, fmaxf(e6, 0.2f * e6));
      e7 = fmaf(bc.w, L2E, fmaxf(e7, 0.2f * e7));
      uint2 d0 = exp4pk(e0, e1, e2, e3);
      uint2 d1 = exp4pk(e4, e5, e6, e7);
      uint4 dd;
      dd.x = d0.x; dd.y = d0.y; dd.z = d1.x; dd.w = d1.y;
      *(uint4*)&Pl[w][pb][row * 64 + wchunk] = dd;
    }
  };

  float4 tA0, tA1, bA0, bA1, bA2, bA3;

  loadTB(jbeg, tA0, tA1, bA0, bA1, bA2, bA3);
  computeP(tA0, tA1, bA0, bA1, bA2, bA3, 0);
  loadTB(jbeg + 64, tA0, tA1, bA0, bA1, bA2, bA3);

  int buf = 0;
  for (int jt = jbeg; jt < jend; jt += 64) {
    const unsigned short* vp = vbase + (size_t)jt * 64;
    short8 v0 = *(const short8*)(vp + 0);
    short8 v1 = *(const short8*)(vp + 256);
    short8 v2 = *(const short8*)(vp + 512);
    short8 v3 = *(const short8*)(vp + 768);
    short8 v4 = *(const short8*)(vp + 2048);
    short8 v5 = *(const short8*)(vp + 2304);
    short8 v6 = *(const short8*)(vp + 2560);
    short8 v7 = *(const short8*)(vp + 2816);
    short8 a0 = *(const short8*)&Pl[w][buf][ra0];
    short8 a1 = *(const short8*)&Pl[w][buf][ra1];
    if (jt + 64 < jend) {
      float4 n0 = tA0, n1 = tA1, m0 = bA0, m1 = bA1, m2 = bA2, m3 = bA3;
      // dead-prefetch clamp inside the bias input allocation (r15 OOB lesson)
      int jn = (jt + 128 < jend) ? (jt + 128) : jbeg;
      loadTB(jn, tA0, tA1, bA0, bA1, bA2, bA3);
      computeP(n0, n1, m0, m1, m2, m3, buf ^ 1);
    }
    __builtin_amdgcn_s_setprio(1);
    accS = __builtin_amdgcn_mfma_f32_16x16x32_bf16(a0, ones.v, accS, 0, 0, 0);
    acc[0] = __builtin_amdgcn_mfma_f32_16x16x32_bf16(a0, v0, acc[0], 0, 0, 0);
    acc[1] = __builtin_amdgcn_mfma_f32_16x16x32_bf16(a0, v1, acc[1], 0, 0, 0);
    acc[2] = __builtin_amdgcn_mfma_f32_16x16x32_bf16(a0, v2, acc[2], 0, 0, 0);
    acc[3] = __builtin_amdgcn_mfma_f32_16x16x32_bf16(a0, v3, acc[3], 0, 0, 0);
    accS = __builtin_amdgcn_mfma_f32_16x16x32_bf16(a1, ones.v, accS, 0, 0, 0);
    acc[0] = __builtin_amdgcn_mfma_f32_16x16x32_bf16(a1, v4, acc[0], 0, 0, 0);
    acc[1] = __builtin_amdgcn_mfma_f32_16x16x32_bf16(a1, v5, acc[1], 0, 0, 0);
    acc[2] = __builtin_amdgcn_mfma_f32_16x16x32_bf16(a1, v6, acc[2], 0, 0, 0);
    acc[3] = __builtin_amdgcn_mfma_f32_16x16x32_bf16(a1, v7, acc[3], 0, 0, 0);
    __builtin_amdgcn_s_setprio(0);
    buf ^= 1;
  }

  // ---- merge: Pl dead; overlay. Per head, 2-way j-merge. ----
  __syncthreads();
  if (li == 0) {
#pragma unroll
    for (int r = 0; r < 4; r++) sLa[w][lg * 4 + r] = accS[r];
  }
#pragma unroll
  for (int hp2 = 0; hp2 < 2; hp2++) {
    if (hp == hp2) {
#pragma unroll
      for (int f = 0; f < 4; f++)
#pragma unroll
        for (int r = 0; r < 4; r++) accL2[jh][lg * 4 + r][f * 16 + li] = acc[f][r];
    }
    __syncthreads();
    {
      int rr = t >> 4, cq = t & 15;
      float S = sLa[2 * hp2][rr] + sLa[2 * hp2 + 1][rr];
      float inv = 1.0f / S;
      size_t ixb = ((size_t)b * NN + i0 + rr) * DD + (h0 + hp2) * 64 + cq;
#pragma unroll
      for (int f = 0; f < 4; f++) {
        int col = f * 16 + cq;
        float O = accL2[0][rr][col] + accL2[1][rr][col];
        out[ixb + f * 16] = O * inv + res[ixb + f * 16];
      }
    }
    __syncthreads();
  }
}

// ------ layer-2 PV: 64-j steps, fp32 bias, dbuf P in LDS; merge OVERLAYS Pl ----
template <int HN, int CCH>
__global__ __launch_bounds__(256) void pv_kernel(
    const unsigned short* __restrict__ hbT, const float* __restrict__ bias,
    const float* __restrict__ sArr, const float* __restrict__ tArr,
    const float* __restrict__ res, float* __restrict__ out) {
  constexpr int DH = DD / HN;
  __shared__ __align__(16) unsigned char smem[16640];
  unsigned short (*Pl)[2][1024] = (unsigned short (*)[2][1024])smem;  // [4][2][1024]
  float (*accL)[16][33] = (float (*)[16][33])smem;                    // [4][16][33]
  float (*sLa)[16] = (float (*)[16])(smem + 8448);                    // [4][16]
  int t = threadIdx.x, w = t >> 6, l = t & 63;
  int li = l & 15, lg = l >> 4;
  int i0 = blockIdx.x * 16;
  int ck = blockIdx.y, bh = blockIdx.z;
  int h = bh % HN, b = bh / HN;
  int c0 = h * DH + ck * (CCH * 64);
  size_t bhN = (size_t)bh * NN;
  const float* trow = tArr + bhN;

  int rs = l >> 3, js = (l & 7) * 8, jc = l & 7;
  int wchunk = ((jc & 4) | ((jc & 3) ^ (rs & 3))) * 8;  // swizzled chunk (shorts)
  float sv[2];
  sv[0] = sArr[bhN + i0 + rs];
  sv[1] = sArr[bhN + i0 + 8 + rs];
  const float* bb0 = bias + ((size_t)b * NN + i0 + rs) * NN;
  const float* bb1 = bb0 + (size_t)8 * NN;

  const unsigned short* vbase =
      hbT + ((size_t)(b * (DD / 64) + (c0 >> 6)) * (NN / 16)) * 1024 +
      (lg >> 1) * 1024 + li * 16 + (lg & 1) * 8;
  int ra0 = li * 64 + (lg ^ (li & 3)) * 8;
  int ra1 = ra0 + 32;

  union { short8 v; unsigned short q[8]; } ones;
#pragma unroll
  for (int k = 0; k < 8; k++) ones.q[k] = 0x3F80;

  const int jbeg = w * (NN / 4), jend = jbeg + NN / 4;
  f32x4 acc[CCH][4] = {};
  f32x4 accS = {0.f, 0.f, 0.f, 0.f};

  auto loadTB = [&](int j, float4& t0, float4& t1, float4& b0a, float4& b0b,
                    float4& b1a, float4& b1b) {
    t0 = *(const float4*)&trow[j + js];
    t1 = *(const float4*)&trow[j + js + 4];
    b0a = *(const float4*)&bb0[j + js];
    b0b = *(const float4*)&bb0[j + js + 4];
    b1a = *(const float4*)&bb1[j + js];
    b1b = *(const float4*)&bb1[j + js + 4];
  };
  auto computeP = [&](const float4& t0, const float4& t1, const float4& b0a,
                      const float4& b0b, const float4& b1a, const float4& b1b, int pb) {
#pragma unroll
    for (int u = 0; u < 2; u++) {
      const float4& ba = u ? b1a : b0a;
      const float4& bc = u ? b1b : b0b;
      int row = u * 8 + rs;
      float e0 = sv[u] + t0.x, e1 = sv[u] + t0.y;
      float e2 = sv[u] + t0.z, e3 = sv[u] + t0.w;
      float e4 = sv[u] + t1.x, e5 = sv[u] + t1.y;
      float e6 = sv[u] + t1.z, e7 = sv[u] + t1.w;
      e0 = fmaf(ba.x, L2E, fmaxf(e0, 0.2f * e0));
      e1 = fmaf(ba.y, L2E, fmaxf(e1, 0.2f * e1));
      e2 = fmaf(ba.z, L2E, fmaxf(e2, 0.2f * e2));
      e3 = fmaf(ba.w, L2E, fmaxf(e3, 0.2f * e3));
      e4 = fmaf(bc.x, L2E, fmaxf(e4, 0.2f * e4));
      e5 = fmaf(bc.y, L2E, fmaxf(e5, 0.2f * e5));
      e6 = fmaf(bc.z, L2E, fmaxf(e6, 0.2f * e6));
      e7 = fmaf(bc.w, L2E, fmaxf(e7, 0.2f * e7));
      uint2 d0 = exp4pk(e0, e1, e2, e3);
      uint2 d1 = exp4pk(e4, e5, e6, e7);
      uint4 dd;
      dd.x = d0.x; dd.y = d0.y; dd.z = d1.x; dd.w = d1.y;
      *(uint4*)&Pl[w][pb][row * 64 + wchunk] = dd;
    }
  };
  auto loadV = [&](int jt, short8 (&vv)[CCH][8]) {
#pragma unroll
    for (int cc = 0; cc < CCH; cc++) {
      const unsigned short* vp =
          vbase + (size_t)cc * ((NN / 16) * 1024) + (size_t)jt * 64;
#pragma unroll
      for (int f = 0; f < 4; f++) {
        vv[cc][f] = *(const short8*)(vp + f * 256);
        vv[cc][4 + f] = *(const short8*)(vp + 2048 + f * 256);
      }
    }
  };
  auto domfma = [&](short8 a0, short8 a1, const short8 (&vv)[CCH][8]) {
    __builtin_amdgcn_s_setprio(1);
    accS = __builtin_amdgcn_mfma_f32_16x16x32_bf16(a0, ones.v, accS, 0, 0, 0);
#pragma unroll
    for (int cc = 0; cc < CCH; cc++)
#pragma unroll
      for (int f = 0; f < 4; f++)
        acc[cc][f] =
            __builtin_amdgcn_mfma_f32_16x16x32_bf16(a0, vv[cc][f], acc[cc][f], 0, 0, 0);
    accS = __builtin_amdgcn_mfma_f32_16x16x32_bf16(a1, ones.v, accS, 0, 0, 0);
#pragma unroll
    for (int cc = 0; cc < CCH; cc++)
#pragma unroll
      for (int f = 0; f < 4; f++)
        acc[cc][f] =
            __builtin_amdgcn_mfma_f32_16x16x32_bf16(a1, vv[cc][4 + f], acc[cc][f], 0, 0, 0);
    __builtin_amdgcn_s_setprio(0);
  };

  float4 tA0, tA1, bA0, bA1, bA2, bA3;
  short8 vv[CCH][8];

  loadTB(jbeg, tA0, tA1, bA0, bA1, bA2, bA3);
  computeP(tA0, tA1, bA0, bA1, bA2, bA3, 0);
  loadTB(jbeg + 64, tA0, tA1, bA0, bA1, bA2, bA3);

  int buf = 0;
  for (int jt = jbeg; jt < jend; jt += 64) {
    loadV(jt, vv);
    short8 a0 = *(const short8*)&Pl[w][buf][ra0];
    short8 a1 = *(const short8*)&Pl[w][buf][ra1];
    if (jt + 64 < jend) {
      float4 n0 = tA0, n1 = tA1, m0 = bA0, m1 = bA1, m2 = bA2, m3 = bA3;
      int jn = (jt + 128 < jend) ? (jt + 128) : jbeg;  // dead-prefetch clamp
      loadTB(jn, tA0, tA1, bA0, bA1, bA2, bA3);
      computeP(n0, n1, m0, m1, m2, m3, buf ^ 1);
    }
    domfma(a0, a1, vv);
    buf ^= 1;
  }

  __syncthreads();  // Pl dead; merge overlays it
  if (li == 0) {
#pragma unroll
    for (int r = 0; r < 4; r++) sLa[w][lg * 4 + r] = accS[r];
  }
#pragma unroll
  for (int g = 0; g < 2 * CCH; g++) {
    int cc = g >> 1, half = g & 1;
#pragma unroll
    for (int f = 0; f < 2; f++)
#pragma unroll
      for (int r = 0; r < 4; r++)
        accL[w][lg * 4 + r][f * 16 + li] = acc[cc][half * 2 + f][r];
    __syncthreads();
    {
      int rr = t >> 4, cp = (t & 15) * 2;
      float S = sLa[0][rr] + sLa[1][rr] + sLa[2][rr] + sLa[3][rr];
      float inv = 1.0f / S;
      float2 O = {0.f, 0.f};
#pragma unroll
      for (int w2 = 0; w2 < 4; w2++) {
        O.x += accL[w2][rr][cp];
        O.y += accL[w2][rr][cp + 1];
      }
      size_t ix = ((size_t)b * NN + i0 + rr) * DD + c0 + cc * 64 + half * 32 + cp;
      float2 rv = *(const float2*)&res[ix];
      float2 ov = {O.x * inv + rv.x, O.y * inv + rv.y};
      *(float2*)&out[ix] = ov;
    }
    __syncthreads();
  }
}

extern "C" void kernel_launch(void* const* d_in, const int* in_sizes, int n_in,
                              void* d_out, int out_size, void* d_ws, size_t ws_size,
                              hipStream_t stream) {
  const float* x = (const float*)d_in[0];
  const float* bias = (const float*)d_in[1];
  const float* W1 = (const float*)d_in[2];
  const float* asrc1 = (const float*)d_in[3];
  const float* adst1 = (const float*)d_in[4];
  const float* g1 = (const float*)d_in[5];
  const float* b1 = (const float*)d_in[6];
  const float* W2 = (const float*)d_in[7];
  const float* asrc2 = (const float*)d_in[8];
  const float* adst2 = (const float*)d_in[9];
  const float* g2 = (const float*)d_in[10];
  const float* b2 = (const float*)d_in[11];
  float* out = (float*)d_out;
  float* ws = (float*)d_ws;

  const size_t RC = (size_t)NB * NN * DD;  // 2097152 floats
  float* attnBuf = ws;                                        // 8 MB fp32
  unsigned short* lnB = (unsigned short*)(ws + RC);           // 4 MB bf16
  unsigned short* hbT = (unsigned short*)(ws + RC + RC / 2);  // 4 MB bf16 tiled V
  unsigned short* WT1 = (unsigned short*)(ws + 2 * RC);       // 0.5 MB
  unsigned short* WT2 = WT1 + (size_t)DD * DD;                // 0.5 MB
  float* vs1 = (float*)(WT2 + (size_t)DD * DD);               // [8][512]
  float* vd1 = vs1 + 8 * DD;
  float* vs2 = vd1 + 8 * DD;  // [1][512]
  float* vd2 = vs2 + DD;
  float* sBuf = vd2 + DD;  // [16][2048]
  float* tBuf = sBuf + 16 * NN;

  const int rows = NB * NN;  // 4096

  hipLaunchKernelGGL(prep_kernel, dim3(128 + 72), dim3(256), 0, stream, W1, W2, WT1, WT2,
                     asrc1, adst1, vs1, vd1, asrc2, adst2, vs2, vd2);

  // ---- layer 1 (H=8, Dh=64) ----
  hipLaunchKernelGGL(lnst_kernel, dim3(rows), dim3(256), 0, stream, x, g1, b1, lnB, vs1, vd1,
                     sBuf, tBuf, 8);
  hipLaunchKernelGGL(gemm_kernel, dim3(256, 8), dim3(256), 0, stream, lnB, WT1, hbT);
  hipLaunchKernelGGL(pvg_kernel, dim3(128, 4, 2), dim3(256), 0, stream, hbT, bias, sBuf,
                     tBuf, x, attnBuf);

  // ---- layer 2 (H=1, Dh=512) ----
  hipLaunchKernelGGL(lnst_kernel, dim3(rows), dim3(256), 0, stream, attnBuf, g2, b2, lnB, vs2,
                     vd2, sBuf, tBuf, 1);
  hipLaunchKernelGGL(gemm_kernel, dim3(256, 8), dim3(256), 0, stream, lnB, WT2, hbT);
  hipLaunchKernelGGL((pv_kernel<1, 2>), dim3(128, 4, 2), dim3(256), 0, stream, hbT, bias,
                     sBuf, tBuf, attnBuf, out);
}